// Round 9
// baseline (119.241 us; speedup 1.0000x reference)
//
#include <hip/hip_runtime.h>
#include <math.h>

#define KMASK 0xFFFF8000u
#define IMASK 0x7FFFu

__device__ __forceinline__ float wave_reduce_sum(float v) {
    #pragma unroll
    for (int off = 32; off >= 1; off >>= 1) v += __shfl_xor(v, off, 64);
    return v;
}

__device__ __forceinline__ unsigned wave_min_u32(unsigned v) {
    #pragma unroll
    for (int off = 32; off >= 1; off >>= 1) {
        unsigned o = (unsigned)__shfl_xor((int)v, off, 64);
        v = (o < v) ? o : v;
    }
    return v;
}

// reductions over aligned 16-lane group (xor 8,4,2,1 stays in-group)
__device__ __forceinline__ unsigned gmin16(unsigned v) {
    #pragma unroll
    for (int off = 8; off >= 1; off >>= 1) {
        unsigned o = (unsigned)__shfl_xor((int)v, off, 64);
        v = (o < v) ? o : v;
    }
    return v;
}
__device__ __forceinline__ float gsum16(float v) {
    #pragma unroll
    for (int off = 8; off >= 1; off >>= 1) v += __shfl_xor(v, off, 64);
    return v;
}

// sorted ascending insert of packed key into 4-element list
__device__ __forceinline__ void insert4u(unsigned k, unsigned (&b)[4]) {
    const bool c0 = k < b[0], c1 = k < b[1], c2 = k < b[2], c3 = k < b[3];
    b[3] = c2 ? b[2] : (c3 ? k : b[3]);
    b[2] = c1 ? b[1] : (c2 ? k : b[2]);
    b[1] = c0 ? b[0] : (c1 ? k : b[1]);
    b[0] = c0 ? k : b[0];
}

__device__ __forceinline__ int cell_of(float x, int G) {
    int c = (int)(x * (float)G);
    return (c < 0) ? 0 : ((c >= G) ? G - 1 : c);
}

__device__ __forceinline__ float dot2(float2 a, float2 b) {
    return fmaf(a.y, b.y, a.x * b.x);
}

// ================= build: one block per direction, grid in LDS =================
// LDS layout: cnt[G3+1] then scr[1024]. Count -> scan -> st write -> scatter.

__global__ __launch_bounds__(1024)
void build_grids(const float* __restrict__ cA, int nA, int GA, int* __restrict__ stA,
                 float4* __restrict__ soA, int* __restrict__ siA,
                 const float* __restrict__ cB, int nB, int GB, int* __restrict__ stB,
                 float4* __restrict__ soB, int* __restrict__ siB,
                 float* __restrict__ part, unsigned* __restrict__ ticket)
{
    extern __shared__ int lds[];
    const bool b0 = (blockIdx.x == 0);
    const float* c = b0 ? cA : cB;
    const int    n = b0 ? nA : nB;
    const int    G = b0 ? GA : GB;
    int*        st = b0 ? stA : stB;
    float4*     so = b0 ? soA : soB;
    int*        si = b0 ? siA : siB;
    const int   G3 = G * G * G;
    const int    t = threadIdx.x;
    int* cnt = lds;            // G3+1 entries
    int* scr = lds + G3 + 1;   // 1024 entries

    for (int i = t; i <= G3; i += 1024) cnt[i] = 0;
    if (b0 && t < 64) part[t] = 0.0f;
    if (b0 && t == 0) *ticket = 0u;
    __syncthreads();

    // count (LDS atomics)
    for (int p = t; p < n; p += 1024) {
        const int cx = cell_of(c[3*p], G), cy = cell_of(c[3*p+1], G), cz = cell_of(c[3*p+2], G);
        atomicAdd(&cnt[(cz * G + cy) * G + cx + 1], 1);
    }
    __syncthreads();

    // inclusive scan of cnt[0..G3]
    const int len = G3 + 1;
    const int chunk = (len + 1023) >> 10;
    const int lo = t * chunk;
    const int hi = (lo + chunk < len) ? (lo + chunk) : len;
    int sum = 0;
    for (int i = lo; i < hi; ++i) sum += cnt[i];
    scr[t] = sum;
    __syncthreads();
    for (int d = 1; d < 1024; d <<= 1) {
        const int v = (t >= d) ? scr[t - d] : 0;
        __syncthreads();
        scr[t] += v;
        __syncthreads();
    }
    int run = (t > 0) ? scr[t - 1] : 0;
    for (int i = lo; i < hi; ++i) {
        run += cnt[i];
        cnt[i] = run;          // cnt[cell] = start of cell (cursor)
        st[i] = run;           // global starts array
    }
    __syncthreads();

    // scatter using LDS cursors
    for (int p = t; p < n; p += 1024) {
        const float x = c[3*p], y = c[3*p+1], z = c[3*p+2];
        const int cx = cell_of(x, G), cy = cell_of(y, G), cz = cell_of(z, G);
        const int pos = atomicAdd(&cnt[(cz * G + cy) * G + cx], 1);
        so[pos] = make_float4(x, y, z, x*x + y*y + z*z);
        si[pos] = p;
    }
}

// ============= fused grid KNN + loss + grid-wide reduction =============
// 16 lanes per query: exact KNN (expand box until r4^2 <= margin^2 or full
// cover), cosine/softmax loss, per-wave atomic into part[64], last block
// (ticket) reduces part -> out.

__global__ __launch_bounds__(256)
void knnloss(const float* __restrict__ ci, const float* __restrict__ fi, int Ni,
             const float* __restrict__ cj, const float* __restrict__ fj, int Nj,
             const float4* __restrict__ soA, const int* __restrict__ stA,
             const int* __restrict__ siA, int GA,
             const float4* __restrict__ soB, const int* __restrict__ stB,
             const int* __restrict__ siB, int GB,
             float sc0, float sc1, float* __restrict__ part,
             unsigned* __restrict__ ticket, float* __restrict__ out)
{
    const int sub = threadIdx.x & 15;
    const int qid = (blockIdx.x * 256 + threadIdx.x) >> 4;
    float acc = 0.0f;

    if (qid < Ni + Nj) {
        const bool d0 = (qid < Ni);
        const int p = d0 ? qid : qid - Ni;
        const float*  cq = d0 ? ci  : cj;
        const float4* so = d0 ? soA : soB;
        const int*    st = d0 ? stA : stB;
        const int*    si = d0 ? siA : siB;
        const int      G = d0 ? GA  : GB;
        const int     nd = d0 ? Nj  : Ni;
        const float* fqp = (d0 ? fi : fj) + (size_t)p * 96;
        const float*  fd = d0 ? fj : fi;
        const float scale = d0 ? sc0 : sc1;

        const float qx = cq[3*p], qy = cq[3*p+1], qz = cq[3*p+2];
        const float h = 1.0f / (float)G;
        const int cx = cell_of(qx, G), cy = cell_of(qy, G), cz = cell_of(qz, G);
        const float qq  = qx*qx + qy*qy + qz*qz;
        const float m2x = -2.0f*qx, m2y = -2.0f*qy, m2z = -2.0f*qz;
        unsigned mk0 = ~0u, mk1 = ~0u, mk2 = ~0u, mk3 = ~0u;

        for (int s = 1; ; ++s) {
            const int x0 = max(cx - s, 0), x1 = min(cx + s, G - 1);
            const int y0 = max(cy - s, 0), y1 = min(cy + s, G - 1);
            const int z0 = max(cz - s, 0), z1 = min(cz + s, G - 1);

            unsigned bk[4] = {~0u, ~0u, ~0u, ~0u};
            for (int z = z0; z <= z1; ++z) {
                for (int y = y0; y <= y1; ++y) {
                    const int rb = (z * G + y) * G;
                    const int cs = st[rb + x0];
                    const int ce = st[rb + x1 + 1];
                    for (int cc = cs + sub; cc < ce; cc += 16) {
                        const float4 P = so[cc];
                        const float d2 =
                            fmaf(P.z, m2z, fmaf(P.y, m2y, fmaf(P.x, m2x, P.w))) + qq;
                        const unsigned k =
                            (__float_as_uint(fmaxf(d2, 0.0f)) & KMASK) | (unsigned)cc;
                        insert4u(k, bk);
                    }
                }
            }

            unsigned t0 = bk[0], t1 = bk[1], t2 = bk[2], t3 = bk[3];
            #pragma unroll
            for (int r = 0; r < 4; ++r) {
                const unsigned m = gmin16(t0);
                if (r == 0) mk0 = m; else if (r == 1) mk1 = m;
                else if (r == 2) mk2 = m; else mk3 = m;
                const bool win = (t0 == m);
                t0 = win ? t1 : t0;
                t1 = win ? t2 : t1;
                t2 = win ? t3 : t2;
                t3 = win ? ~0u : t3;
            }

            float margin = 3.0e38f;
            if (x0 > 0)     margin = fminf(margin, qx - (float)x0 * h);
            if (x1 < G - 1) margin = fminf(margin, (float)(x1 + 1) * h - qx);
            if (y0 > 0)     margin = fminf(margin, qy - (float)y0 * h);
            if (y1 < G - 1) margin = fminf(margin, (float)(y1 + 1) * h - qy);
            if (z0 > 0)     margin = fminf(margin, qz - (float)z0 * h);
            if (z1 < G - 1) margin = fminf(margin, (float)(z1 + 1) * h - qz);
            const bool covered = (margin > 1.0e37f);
            const float kd = __uint_as_float(mk3 & KMASK);   // NaN-bits if <4 found
            if (covered || (kd * 1.01f <= margin * margin)) break;  // NaN -> expand
        }

        const int nm1 = nd - 1;
        int ni_[4];
        ni_[0] = si[min((int)(mk0 & IMASK), nm1)];
        ni_[1] = si[min((int)(mk1 & IMASK), nm1)];
        ni_[2] = si[min((int)(mk2 & IMASK), nm1)];
        ni_[3] = si[min((int)(mk3 & IMASK), nm1)];

        // loss: 96 floats = 48 float2, 3 per lane in the 16-group
        const float2* q2 = (const float2*)fqp;
        const float2 qa = q2[3*sub], qb = q2[3*sub+1], qc = q2[3*sub+2];
        const float ssq = gsum16(dot2(qa,qa) + dot2(qb,qb) + dot2(qc,qc));

        float sim[4];
        #pragma unroll
        for (int k = 0; k < 4; ++k) {
            const float2* f2 = (const float2*)(fd + (size_t)ni_[k] * 96);
            const float2 da = f2[3*sub], db = f2[3*sub+1], dc = f2[3*sub+2];
            const float dotv = gsum16(dot2(qa,da) + dot2(qb,db) + dot2(qc,dc));
            const float ssd  = gsum16(dot2(da,da) + dot2(db,db) + dot2(dc,dc));
            sim[k] = dotv * rsqrtf(fmaxf(ssq, 1e-24f) * fmaxf(ssd, 1e-24f)) * 10.0f;
        }
        const float m = fmaxf(fmaxf(sim[0], sim[1]), fmaxf(sim[2], sim[3]));
        const float e0 = __expf(sim[0] - m), e1 = __expf(sim[1] - m);
        const float e2 = __expf(sim[2] - m), e3 = __expf(sim[3] - m);
        const float ssum = e0 + e1 + e2 + e3;
        const float inv = 1.0f / ssum;
        const float p2 = (e0*e0 + e1*e1 + e2*e2 + e3*e3) * inv * inv;
        if (sub == 0) acc = -__logf(p2 + 1e-12f) * scale;
    }

    acc = wave_reduce_sum(acc);
    if ((threadIdx.x & 63) == 0) atomicAdd(&part[blockIdx.x & 63], acc);

    // grid-wide completion via ticket; last block reduces part -> out
    __syncthreads();
    __shared__ unsigned s_done;
    if (threadIdx.x == 0) {
        __threadfence();
        s_done = atomicAdd(ticket, 1u);
    }
    __syncthreads();
    if (s_done == gridDim.x - 1) {
        if (threadIdx.x < 64) {
            float v = atomicAdd(&part[threadIdx.x], 0.0f); // coherent read
            v = wave_reduce_sum(v);
            if (threadIdx.x == 0) out[0] = v;
        }
    }
}

// ============================ brute fallback ============================

#define WPB 4
template<int QPW>
__device__ __forceinline__ void brute_dir(
    const float* __restrict__ cq, const float* __restrict__ fq, int Nq,
    const float* __restrict__ cd, const float* __restrict__ fd, int Nd,
    float scale, float* __restrict__ out, int blk)
{
    const int lane = threadIdx.x & 63;
    const int widx = threadIdx.x >> 6;
    int qbase = (blk * WPB + widx) * QPW;
    if (qbase >= Nq) return;
    qbase = __builtin_amdgcn_readfirstlane(qbase);

    float qx[QPW], qy[QPW], qz[QPW];
    #pragma unroll
    for (int q = 0; q < QPW; ++q) {
        const int qi = (qbase + q < Nq) ? (qbase + q) : (Nq - 1);
        qx[q] = cq[qi*3]; qy[q] = cq[qi*3+1]; qz[q] = cq[qi*3+2];
    }
    unsigned bk[QPW][4];
    #pragma unroll
    for (int q = 0; q < QPW; ++q) {
        #pragma unroll
        for (int k = 0; k < 4; ++k) bk[q][k] = ~0u;
    }
    for (int base = 0; base < Nd; base += 64) {
        const int p = base + lane;
        const int cp = (p < Nd) ? p : (Nd - 1);
        const float px = cd[cp*3], py = cd[cp*3+1], pz = cd[cp*3+2];
        #pragma unroll
        for (int q = 0; q < QPW; ++q) {
            const float dx = px - qx[q], dy = py - qy[q], dz = pz - qz[q];
            const float d2 = dx*dx + dy*dy + dz*dz;
            unsigned k = (__float_as_uint(d2) & KMASK) | (unsigned)p;
            if (p >= Nd) k = ~0u;
            insert4u(k, bk[q]);
        }
    }
    float wacc = 0.0f;
    #pragma unroll
    for (int q = 0; q < QPW; ++q) {
        if (qbase + q >= Nq) break;
        unsigned t0 = bk[q][0], t1 = bk[q][1], t2 = bk[q][2], t3 = bk[q][3];
        int ni_[4];
        #pragma unroll
        for (int k = 0; k < 4; ++k) {
            const unsigned m = wave_min_u32(t0);
            ni_[k] = (int)(m & IMASK);
            const bool win = (t0 == m);
            t0 = win ? t1 : t0; t1 = win ? t2 : t1; t2 = win ? t3 : t2; t3 = win ? ~0u : t3;
        }
        const float* fqp = fq + (size_t)(qbase + q) * 96;
        const float qf0 = fqp[lane];
        const float qf1 = (lane < 32) ? fqp[64 + lane] : 0.0f;
        const float ssq = wave_reduce_sum(qf0*qf0 + qf1*qf1);
        float sim[4];
        #pragma unroll
        for (int k = 0; k < 4; ++k) {
            const float* fdp = fd + (size_t)ni_[k] * 96;
            const float df0 = fdp[lane];
            const float df1 = (lane < 32) ? fdp[64 + lane] : 0.0f;
            const float dotv = wave_reduce_sum(qf0*df0 + qf1*df1);
            const float ssd = wave_reduce_sum(df0*df0 + df1*df1);
            sim[k] = dotv * rsqrtf(fmaxf(ssq, 1e-24f) * fmaxf(ssd, 1e-24f)) * 10.0f;
        }
        const float m = fmaxf(fmaxf(sim[0], sim[1]), fmaxf(sim[2], sim[3]));
        const float e0 = __expf(sim[0]-m), e1 = __expf(sim[1]-m);
        const float e2 = __expf(sim[2]-m), e3 = __expf(sim[3]-m);
        const float ssum = e0+e1+e2+e3;
        const float inv = 1.0f/ssum;
        const float p2 = (e0*e0+e1*e1+e2*e2+e3*e3)*inv*inv;
        wacc += -__logf(p2 + 1e-12f);
    }
    if (lane == 0) atomicAdd(out, wacc * scale);
}

__global__ __launch_bounds__(256)
void brute_fused(const float* __restrict__ ci, const float* __restrict__ fi, int Ni,
                 const float* __restrict__ cj, const float* __restrict__ fj, int Nj,
                 float s0, float s1, int B0, int B1, float* __restrict__ out)
{
    const int bid = (int)blockIdx.x;
    const int bmin = (B0 < B1) ? B0 : B1;
    int dir, blk;
    if (bid < 2 * bmin) { dir = bid & 1; blk = bid >> 1; }
    else { dir = (B0 > B1) ? 0 : 1; blk = bid - bmin; }
    if (dir == 0) brute_dir<8>(ci, fi, Ni, cj, fj, Nj, s0, out, blk);
    else          brute_dir<4>(cj, fj, Nj, ci, fi, Ni, s1, out, blk);
}

// ============================ launch ============================

extern "C" void kernel_launch(void* const* d_in, const int* in_sizes, int n_in,
                              void* d_out, int out_size, void* d_ws, size_t ws_size,
                              hipStream_t stream) {
    const float* feat_i  = (const float*)d_in[0];
    const float* coord_i = (const float*)d_in[1];
    const float* feat_j  = (const float*)d_in[2];
    const float* coord_j = (const float*)d_in[3];
    const int Ni = in_sizes[0] / 96;
    const int Nj = in_sizes[2] / 96;
    float* out = (float*)d_out;

    auto gridfor = [](int n) {
        int g = (int)cbrtf((float)n / 4.5f);
        if (g < 2) g = 2;
        if (g > 24) g = 24;   // LDS: (24^3+1+1024)*4 B = 59.4 KB < 64 KB
        return g;
    };
    const int GA = gridfor(Nj), GB = gridfor(Ni);       // A: db=j, B: db=i
    const int GA3 = GA * GA * GA, GB3 = GB * GB * GB;

    size_t off = 0;
    auto alloc = [&](size_t bytes) { size_t o = off; off = (off + bytes + 15) & ~(size_t)15; return o; };
    const size_t o_soA  = alloc((size_t)Nj * 16);
    const size_t o_soB  = alloc((size_t)Ni * 16);
    const size_t o_siA  = alloc((size_t)Nj * 4);
    const size_t o_siB  = alloc((size_t)Ni * 4);
    const size_t o_stA  = alloc((size_t)(GA3 + 1) * 4);
    const size_t o_stB  = alloc((size_t)(GB3 + 1) * 4);
    const size_t o_part = alloc(64 * 4);
    const size_t o_tick = alloc(16);

    if (ws_size >= off && Ni >= 8 && Nj >= 8 && Ni <= 32000 && Nj <= 32000) {
        char* W = (char*)d_ws;
        float4* soA = (float4*)(W + o_soA);
        float4* soB = (float4*)(W + o_soB);
        int* siA = (int*)(W + o_siA);
        int* siB = (int*)(W + o_siB);
        int* stA = (int*)(W + o_stA);
        int* stB = (int*)(W + o_stB);
        float* part = (float*)(W + o_part);
        unsigned* tick = (unsigned*)(W + o_tick);

        const int G3max = (GA3 > GB3) ? GA3 : GB3;
        const size_t ldsBytes = (size_t)(G3max + 1 + 1024) * 4;

        build_grids<<<2, 1024, ldsBytes, stream>>>(
            coord_j, Nj, GA, stA, soA, siA,
            coord_i, Ni, GB, stB, soB, siB,
            part, tick);

        const int nQ = Ni + Nj;
        const int nblk = (nQ * 16 + 255) / 256;
        knnloss<<<nblk, 256, 0, stream>>>(
            coord_i, feat_i, Ni, coord_j, feat_j, Nj,
            soA, stA, siA, GA, soB, stB, siB, GB,
            0.5f / (float)Ni, 0.5f / (float)Nj, part, tick, out);
    } else {
        hipMemsetAsync(out, 0, sizeof(float), stream);
        const int waves0 = (Ni + 7) / 8;
        const int B0 = (waves0 + WPB - 1) / WPB;
        const int waves1 = (Nj + 3) / 4;
        const int B1 = (waves1 + WPB - 1) / WPB;
        brute_fused<<<B0 + B1, 256, 0, stream>>>(
            coord_i, feat_i, Ni, coord_j, feat_j, Nj,
            0.5f / (float)Ni, 0.5f / (float)Nj, B0, B1, out);
    }
}

// Round 10
// 79.535 us; speedup vs baseline: 1.4992x; 1.4992x over previous
//
#include <hip/hip_runtime.h>
#include <math.h>

#define KMASK 0xFFFF8000u
#define IMASK 0x7FFFu

__device__ __forceinline__ float wave_reduce_sum(float v) {
    #pragma unroll
    for (int off = 32; off >= 1; off >>= 1) v += __shfl_xor(v, off, 64);
    return v;
}

__device__ __forceinline__ unsigned wave_min_u32(unsigned v) {
    #pragma unroll
    for (int off = 32; off >= 1; off >>= 1) {
        unsigned o = (unsigned)__shfl_xor((int)v, off, 64);
        v = (o < v) ? o : v;
    }
    return v;
}

// reductions over aligned 8-lane group (xor 4,2,1 stays in-group)
__device__ __forceinline__ unsigned gmin8(unsigned v) {
    #pragma unroll
    for (int off = 4; off >= 1; off >>= 1) {
        unsigned o = (unsigned)__shfl_xor((int)v, off, 64);
        v = (o < v) ? o : v;
    }
    return v;
}
__device__ __forceinline__ float gsum8(float v) {
    #pragma unroll
    for (int off = 4; off >= 1; off >>= 1) v += __shfl_xor(v, off, 64);
    return v;
}

// sorted ascending insert of packed key into 4-element list
__device__ __forceinline__ void insert4u(unsigned k, unsigned (&b)[4]) {
    const bool c0 = k < b[0], c1 = k < b[1], c2 = k < b[2], c3 = k < b[3];
    b[3] = c2 ? b[2] : (c3 ? k : b[3]);
    b[2] = c1 ? b[1] : (c2 ? k : b[2]);
    b[1] = c0 ? b[0] : (c1 ? k : b[1]);
    b[0] = c0 ? k : b[0];
}

__device__ __forceinline__ int cell_of(float x, int G) {
    int c = (int)(x * (float)G);
    return (c < 0) ? 0 : ((c >= G) ? G - 1 : c);
}

__device__ __forceinline__ float dot4(float4 a, float4 b) {
    return fmaf(a.w, b.w, fmaf(a.z, b.z, fmaf(a.y, b.y, a.x * b.x)));
}

// ================= build: one block per direction, grid in LDS =================

__global__ __launch_bounds__(1024)
void build_grids(const float* __restrict__ cA, int nA, int GA, int* __restrict__ stA,
                 float4* __restrict__ soA, int* __restrict__ siA,
                 const float* __restrict__ cB, int nB, int GB, int* __restrict__ stB,
                 float4* __restrict__ soB, int* __restrict__ siB,
                 float* __restrict__ part)
{
    extern __shared__ int lds[];
    const bool b0 = (blockIdx.x == 0);
    const float* c = b0 ? cA : cB;
    const int    n = b0 ? nA : nB;
    const int    G = b0 ? GA : GB;
    int*        st = b0 ? stA : stB;
    float4*     so = b0 ? soA : soB;
    int*        si = b0 ? siA : siB;
    const int   G3 = G * G * G;
    const int    t = threadIdx.x;
    int* cnt = lds;            // G3+1 entries
    int* scr = lds + G3 + 1;   // 1024 entries

    for (int i = t; i <= G3; i += 1024) cnt[i] = 0;
    if (b0 && t < 64) part[t] = 0.0f;
    __syncthreads();

    for (int p = t; p < n; p += 1024) {
        const int cx = cell_of(c[3*p], G), cy = cell_of(c[3*p+1], G), cz = cell_of(c[3*p+2], G);
        atomicAdd(&cnt[(cz * G + cy) * G + cx + 1], 1);
    }
    __syncthreads();

    const int len = G3 + 1;
    const int chunk = (len + 1023) >> 10;
    const int lo = t * chunk;
    const int hi = (lo + chunk < len) ? (lo + chunk) : len;
    int sum = 0;
    for (int i = lo; i < hi; ++i) sum += cnt[i];
    scr[t] = sum;
    __syncthreads();
    for (int d = 1; d < 1024; d <<= 1) {
        const int v = (t >= d) ? scr[t - d] : 0;
        __syncthreads();
        scr[t] += v;
        __syncthreads();
    }
    int run = (t > 0) ? scr[t - 1] : 0;
    for (int i = lo; i < hi; ++i) {
        run += cnt[i];
        cnt[i] = run;
        st[i] = run;
    }
    __syncthreads();

    for (int p = t; p < n; p += 1024) {
        const float x = c[3*p], y = c[3*p+1], z = c[3*p+2];
        const int cx = cell_of(x, G), cy = cell_of(y, G), cz = cell_of(z, G);
        const int pos = atomicAdd(&cnt[(cz * G + cy) * G + cx], 1);
        so[pos] = make_float4(x, y, z, x*x + y*y + z*z);
        si[pos] = p;
    }
}

// ============= fused grid KNN + loss =============
// 8 lanes per query. Fast path: fully-unrolled 3x3 row-range prefetch (all
// range loads in flight before the sweep). Rare non-converged queries use
// the generic expanding-box loop from s=2.

__global__ __launch_bounds__(256)
void knnloss(const float* __restrict__ ci, const float* __restrict__ fi, int Ni,
             const float* __restrict__ cj, const float* __restrict__ fj, int Nj,
             const float4* __restrict__ soA, const int* __restrict__ stA,
             const int* __restrict__ siA, int GA,
             const float4* __restrict__ soB, const int* __restrict__ stB,
             const int* __restrict__ siB, int GB,
             float sc0, float sc1, float* __restrict__ part)
{
    const int sub = threadIdx.x & 7;
    const int qid = (blockIdx.x * 256 + threadIdx.x) >> 3;
    float acc = 0.0f;

    if (qid < Ni + Nj) {
        const bool d0 = (qid < Ni);
        const int p = d0 ? qid : qid - Ni;
        const float*  cq = d0 ? ci  : cj;
        const float4* so = d0 ? soA : soB;
        const int*    st = d0 ? stA : stB;
        const int*    si = d0 ? siA : siB;
        const int      G = d0 ? GA  : GB;
        const int     nd = d0 ? Nj  : Ni;
        const float* fqp = (d0 ? fi : fj) + (size_t)p * 96;
        const float*  fd = d0 ? fj : fi;
        const float scale = d0 ? sc0 : sc1;

        const float qx = cq[3*p], qy = cq[3*p+1], qz = cq[3*p+2];
        const float h = 1.0f / (float)G;
        const int cx = cell_of(qx, G), cy = cell_of(qy, G), cz = cell_of(qz, G);
        const float qq  = qx*qx + qy*qy + qz*qz;
        const float m2x = -2.0f*qx, m2y = -2.0f*qy, m2z = -2.0f*qz;
        unsigned mk[4];

        // ---------- fast path: s = 1, 3x3 rows prefetched ----------
        {
            const int x0 = max(cx - 1, 0), x1 = min(cx + 1, G - 1);
            int csr[9], cer[9];
            #pragma unroll
            for (int dz = 0; dz < 3; ++dz) {
                #pragma unroll
                for (int dy = 0; dy < 3; ++dy) {
                    const int zz = cz + dz - 1, yy = cy + dy - 1;
                    const bool v = ((unsigned)zz < (unsigned)G) & ((unsigned)yy < (unsigned)G);
                    const int rb = v ? (zz * G + yy) * G : 0;
                    csr[dz*3+dy] = v ? st[rb + x0] : 0;
                    cer[dz*3+dy] = v ? st[rb + x1 + 1] : 0;
                }
            }
            unsigned bk[4] = {~0u, ~0u, ~0u, ~0u};
            #pragma unroll
            for (int r = 0; r < 9; ++r) {
                for (int cc = csr[r] + sub; cc < cer[r]; cc += 8) {
                    const float4 P = so[cc];
                    const float d2 =
                        fmaf(P.z, m2z, fmaf(P.y, m2y, fmaf(P.x, m2x, P.w))) + qq;
                    const unsigned k =
                        (__float_as_uint(fmaxf(d2, 0.0f)) & KMASK) | (unsigned)cc;
                    insert4u(k, bk);
                }
            }
            unsigned t0 = bk[0], t1 = bk[1], t2 = bk[2], t3 = bk[3];
            #pragma unroll
            for (int r = 0; r < 4; ++r) {
                const unsigned m = gmin8(t0);
                mk[r] = m;
                const bool win = (t0 == m);
                t0 = win ? t1 : t0;
                t1 = win ? t2 : t1;
                t2 = win ? t3 : t2;
                t3 = win ? ~0u : t3;
            }
            const int y0 = max(cy - 1, 0), y1 = min(cy + 1, G - 1);
            const int z0 = max(cz - 1, 0), z1 = min(cz + 1, G - 1);
            float margin = 3.0e38f;
            if (x0 > 0)     margin = fminf(margin, qx - (float)x0 * h);
            if (x1 < G - 1) margin = fminf(margin, (float)(x1 + 1) * h - qx);
            if (y0 > 0)     margin = fminf(margin, qy - (float)y0 * h);
            if (y1 < G - 1) margin = fminf(margin, (float)(y1 + 1) * h - qy);
            if (z0 > 0)     margin = fminf(margin, qz - (float)z0 * h);
            if (z1 < G - 1) margin = fminf(margin, (float)(z1 + 1) * h - qz);
            const bool covered = (margin > 1.0e37f);
            const float kd = __uint_as_float(mk[3] & KMASK);
            const bool ok = covered || (kd * 1.01f <= margin * margin);

            // ---------- slow path (rare): expanding box from s = 2 ----------
            if (!ok) {
                for (int s = 2; ; ++s) {
                    const int sx0 = max(cx - s, 0), sx1 = min(cx + s, G - 1);
                    const int sy0 = max(cy - s, 0), sy1 = min(cy + s, G - 1);
                    const int sz0 = max(cz - s, 0), sz1 = min(cz + s, G - 1);
                    unsigned b2[4] = {~0u, ~0u, ~0u, ~0u};
                    for (int z = sz0; z <= sz1; ++z) {
                        for (int y = sy0; y <= sy1; ++y) {
                            const int rb = (z * G + y) * G;
                            const int cs = st[rb + sx0];
                            const int ce = st[rb + sx1 + 1];
                            for (int cc = cs + sub; cc < ce; cc += 8) {
                                const float4 P = so[cc];
                                const float d2 =
                                    fmaf(P.z, m2z, fmaf(P.y, m2y, fmaf(P.x, m2x, P.w))) + qq;
                                const unsigned k =
                                    (__float_as_uint(fmaxf(d2, 0.0f)) & KMASK) | (unsigned)cc;
                                insert4u(k, b2);
                            }
                        }
                    }
                    unsigned u0 = b2[0], u1 = b2[1], u2 = b2[2], u3 = b2[3];
                    #pragma unroll
                    for (int r = 0; r < 4; ++r) {
                        const unsigned m = gmin8(u0);
                        mk[r] = m;
                        const bool win = (u0 == m);
                        u0 = win ? u1 : u0;
                        u1 = win ? u2 : u1;
                        u2 = win ? u3 : u2;
                        u3 = win ? ~0u : u3;
                    }
                    float mg = 3.0e38f;
                    if (sx0 > 0)     mg = fminf(mg, qx - (float)sx0 * h);
                    if (sx1 < G - 1) mg = fminf(mg, (float)(sx1 + 1) * h - qx);
                    if (sy0 > 0)     mg = fminf(mg, qy - (float)sy0 * h);
                    if (sy1 < G - 1) mg = fminf(mg, (float)(sy1 + 1) * h - qy);
                    if (sz0 > 0)     mg = fminf(mg, qz - (float)sz0 * h);
                    if (sz1 < G - 1) mg = fminf(mg, (float)(sz1 + 1) * h - qz);
                    const bool cov = (mg > 1.0e37f);
                    const float k2 = __uint_as_float(mk[3] & KMASK);
                    if (cov || (k2 * 1.01f <= mg * mg)) break;
                }
            }
        }

        const int nm1 = nd - 1;
        int ni_[4];
        #pragma unroll
        for (int k = 0; k < 4; ++k) ni_[k] = si[min((int)(mk[k] & IMASK), nm1)];

        // loss: 96 floats = 24 float4, 3 per lane in the 8-group
        const float4* q4 = (const float4*)fqp;
        const float4 qa = q4[3*sub], qb = q4[3*sub+1], qc = q4[3*sub+2];
        const float ssq = gsum8(dot4(qa,qa) + dot4(qb,qb) + dot4(qc,qc));

        float sim[4];
        #pragma unroll
        for (int k = 0; k < 4; ++k) {
            const float4* f4 = (const float4*)(fd + (size_t)ni_[k] * 96);
            const float4 da = f4[3*sub], db = f4[3*sub+1], dc = f4[3*sub+2];
            const float dotv = gsum8(dot4(qa,da) + dot4(qb,db) + dot4(qc,dc));
            const float ssd  = gsum8(dot4(da,da) + dot4(db,db) + dot4(dc,dc));
            sim[k] = dotv * rsqrtf(fmaxf(ssq, 1e-24f) * fmaxf(ssd, 1e-24f)) * 10.0f;
        }
        const float m = fmaxf(fmaxf(sim[0], sim[1]), fmaxf(sim[2], sim[3]));
        const float e0 = __expf(sim[0] - m), e1 = __expf(sim[1] - m);
        const float e2 = __expf(sim[2] - m), e3 = __expf(sim[3] - m);
        const float ssum = e0 + e1 + e2 + e3;
        const float inv = 1.0f / ssum;
        const float p2 = (e0*e0 + e1*e1 + e2*e2 + e3*e3) * inv * inv;
        if (sub == 0) acc = -__logf(p2 + 1e-12f) * scale;
    }

    acc = wave_reduce_sum(acc);
    if ((threadIdx.x & 63) == 0) atomicAdd(&part[blockIdx.x & 63], acc);
}

__global__ __launch_bounds__(64)
void final_sum(const float* __restrict__ partial, float* __restrict__ out) {
    float v = partial[threadIdx.x];
    v = wave_reduce_sum(v);
    if (threadIdx.x == 0) out[0] = v;
}

// ============================ brute fallback ============================

#define WPB 4
template<int QPW>
__device__ __forceinline__ void brute_dir(
    const float* __restrict__ cq, const float* __restrict__ fq, int Nq,
    const float* __restrict__ cd, const float* __restrict__ fd, int Nd,
    float scale, float* __restrict__ out, int blk)
{
    const int lane = threadIdx.x & 63;
    const int widx = threadIdx.x >> 6;
    int qbase = (blk * WPB + widx) * QPW;
    if (qbase >= Nq) return;
    qbase = __builtin_amdgcn_readfirstlane(qbase);

    float qx[QPW], qy[QPW], qz[QPW];
    #pragma unroll
    for (int q = 0; q < QPW; ++q) {
        const int qi = (qbase + q < Nq) ? (qbase + q) : (Nq - 1);
        qx[q] = cq[qi*3]; qy[q] = cq[qi*3+1]; qz[q] = cq[qi*3+2];
    }
    unsigned bk[QPW][4];
    #pragma unroll
    for (int q = 0; q < QPW; ++q) {
        #pragma unroll
        for (int k = 0; k < 4; ++k) bk[q][k] = ~0u;
    }
    for (int base = 0; base < Nd; base += 64) {
        const int p = base + lane;
        const int cp = (p < Nd) ? p : (Nd - 1);
        const float px = cd[cp*3], py = cd[cp*3+1], pz = cd[cp*3+2];
        #pragma unroll
        for (int q = 0; q < QPW; ++q) {
            const float dx = px - qx[q], dy = py - qy[q], dz = pz - qz[q];
            const float d2 = dx*dx + dy*dy + dz*dz;
            unsigned k = (__float_as_uint(d2) & KMASK) | (unsigned)p;
            if (p >= Nd) k = ~0u;
            insert4u(k, bk[q]);
        }
    }
    float wacc = 0.0f;
    #pragma unroll
    for (int q = 0; q < QPW; ++q) {
        if (qbase + q >= Nq) break;
        unsigned t0 = bk[q][0], t1 = bk[q][1], t2 = bk[q][2], t3 = bk[q][3];
        int ni_[4];
        #pragma unroll
        for (int k = 0; k < 4; ++k) {
            const unsigned m = wave_min_u32(t0);
            ni_[k] = (int)(m & IMASK);
            const bool win = (t0 == m);
            t0 = win ? t1 : t0; t1 = win ? t2 : t1; t2 = win ? t3 : t2; t3 = win ? ~0u : t3;
        }
        const float* fqp = fq + (size_t)(qbase + q) * 96;
        const float qf0 = fqp[lane];
        const float qf1 = (lane < 32) ? fqp[64 + lane] : 0.0f;
        const float ssq = wave_reduce_sum(qf0*qf0 + qf1*qf1);
        float sim[4];
        #pragma unroll
        for (int k = 0; k < 4; ++k) {
            const float* fdp = fd + (size_t)ni_[k] * 96;
            const float df0 = fdp[lane];
            const float df1 = (lane < 32) ? fdp[64 + lane] : 0.0f;
            const float dotv = wave_reduce_sum(qf0*df0 + qf1*df1);
            const float ssd = wave_reduce_sum(df0*df0 + df1*df1);
            sim[k] = dotv * rsqrtf(fmaxf(ssq, 1e-24f) * fmaxf(ssd, 1e-24f)) * 10.0f;
        }
        const float m = fmaxf(fmaxf(sim[0], sim[1]), fmaxf(sim[2], sim[3]));
        const float e0 = __expf(sim[0]-m), e1 = __expf(sim[1]-m);
        const float e2 = __expf(sim[2]-m), e3 = __expf(sim[3]-m);
        const float ssum = e0+e1+e2+e3;
        const float inv = 1.0f/ssum;
        const float p2 = (e0*e0+e1*e1+e2*e2+e3*e3)*inv*inv;
        wacc += -__logf(p2 + 1e-12f);
    }
    if (lane == 0) atomicAdd(out, wacc * scale);
}

__global__ __launch_bounds__(256)
void brute_fused(const float* __restrict__ ci, const float* __restrict__ fi, int Ni,
                 const float* __restrict__ cj, const float* __restrict__ fj, int Nj,
                 float s0, float s1, int B0, int B1, float* __restrict__ out)
{
    const int bid = (int)blockIdx.x;
    const int bmin = (B0 < B1) ? B0 : B1;
    int dir, blk;
    if (bid < 2 * bmin) { dir = bid & 1; blk = bid >> 1; }
    else { dir = (B0 > B1) ? 0 : 1; blk = bid - bmin; }
    if (dir == 0) brute_dir<8>(ci, fi, Ni, cj, fj, Nj, s0, out, blk);
    else          brute_dir<4>(cj, fj, Nj, ci, fi, Ni, s1, out, blk);
}

// ============================ launch ============================

extern "C" void kernel_launch(void* const* d_in, const int* in_sizes, int n_in,
                              void* d_out, int out_size, void* d_ws, size_t ws_size,
                              hipStream_t stream) {
    const float* feat_i  = (const float*)d_in[0];
    const float* coord_i = (const float*)d_in[1];
    const float* feat_j  = (const float*)d_in[2];
    const float* coord_j = (const float*)d_in[3];
    const int Ni = in_sizes[0] / 96;
    const int Nj = in_sizes[2] / 96;
    float* out = (float*)d_out;

    auto gridfor = [](int n) {
        int g = (int)cbrtf((float)n / 4.5f);
        if (g < 2) g = 2;
        if (g > 24) g = 24;   // LDS: (24^3+1+1024)*4 B = 59.4 KB < 64 KB
        return g;
    };
    const int GA = gridfor(Nj), GB = gridfor(Ni);       // A: db=j, B: db=i
    const int GA3 = GA * GA * GA, GB3 = GB * GB * GB;

    size_t off = 0;
    auto alloc = [&](size_t bytes) { size_t o = off; off = (off + bytes + 15) & ~(size_t)15; return o; };
    const size_t o_soA  = alloc((size_t)Nj * 16);
    const size_t o_soB  = alloc((size_t)Ni * 16);
    const size_t o_siA  = alloc((size_t)Nj * 4);
    const size_t o_siB  = alloc((size_t)Ni * 4);
    const size_t o_stA  = alloc((size_t)(GA3 + 1) * 4);
    const size_t o_stB  = alloc((size_t)(GB3 + 1) * 4);
    const size_t o_part = alloc(64 * 4);

    if (ws_size >= off && Ni >= 8 && Nj >= 8 && Ni <= 32000 && Nj <= 32000) {
        char* W = (char*)d_ws;
        float4* soA = (float4*)(W + o_soA);
        float4* soB = (float4*)(W + o_soB);
        int* siA = (int*)(W + o_siA);
        int* siB = (int*)(W + o_siB);
        int* stA = (int*)(W + o_stA);
        int* stB = (int*)(W + o_stB);
        float* part = (float*)(W + o_part);

        const int G3max = (GA3 > GB3) ? GA3 : GB3;
        const size_t ldsBytes = (size_t)(G3max + 1 + 1024) * 4;

        build_grids<<<2, 1024, ldsBytes, stream>>>(
            coord_j, Nj, GA, stA, soA, siA,
            coord_i, Ni, GB, stB, soB, siB,
            part);

        const int nQ = Ni + Nj;
        const int nblk = (nQ * 8 + 255) / 256;
        knnloss<<<nblk, 256, 0, stream>>>(
            coord_i, feat_i, Ni, coord_j, feat_j, Nj,
            soA, stA, siA, GA, soB, stB, siB, GB,
            0.5f / (float)Ni, 0.5f / (float)Nj, part);
        final_sum<<<1, 64, 0, stream>>>(part, out);
    } else {
        hipMemsetAsync(out, 0, sizeof(float), stream);
        const int waves0 = (Ni + 7) / 8;
        const int B0 = (waves0 + WPB - 1) / WPB;
        const int waves1 = (Nj + 3) / 4;
        const int B1 = (waves1 + WPB - 1) / WPB;
        brute_fused<<<B0 + B1, 256, 0, stream>>>(
            coord_i, feat_i, Ni, coord_j, feat_j, Nj,
            0.5f / (float)Ni, 0.5f / (float)Nj, B0, B1, out);
    }
}